// Round 5
// baseline (132.828 us; speedup 1.0000x reference)
//
#include <hip/hip_runtime.h>

// GNNDecoder: x_hat = GE[batch] @ node_w.T + node_b ; edge_hat = GE[batch[src]] @ edge_w.T + edge_b
// Structure: per-graph projections P=[B,FN], Q=[B,FE] (tiny GEMM), then outputs are
// pure row-gathers (memory-bound, 512MB nt-stores).
// R5 (from proven R2 base, one structural change in the scatters):
//  - node scatter: batch is SORTED -> a block's contiguous row slice spans ~3 graphs.
//    Stage ids + the few P rows in LDS BEFORE any store; hot loop = ds_read + nt-store,
//    no vmcnt-dependent loads (vmcnt retires in order, so gather loads otherwise
//    stall on the nt-store queue).
//  - edge scatter: stage eid[e]=batch[src[e]] per block (hoists 2 of 3 dependent
//    loads out of the hot loop; staging happens before any store is issued).

#define H   256
#define FN  128
#define FE  64
#define GPB 8     // graphs per proj block
#define MAXG 32   // max staged P rows per node block

typedef float f4 __attribute__((ext_vector_type(4)));

__global__ __launch_bounds__(192) void proj_kernel(
    const float* __restrict__ ge,      // [B, H]
    const float* __restrict__ node_w,  // [FN, H]
    const float* __restrict__ node_b,  // [FN]
    const float* __restrict__ edge_w,  // [FE, H]
    const float* __restrict__ edge_b,  // [FE]
    float* __restrict__ P,             // [B, FN]
    float* __restrict__ Q)             // [B, FE]
{
    __shared__ float sge[GPB * H];
    const int t  = threadIdx.x;            // 0..191; waves 0,1 = node cols, wave 2 = edge cols
    const int g0 = blockIdx.x * GPB;

    const float4* ge4  = reinterpret_cast<const float4*>(ge + (size_t)g0 * H);
    float4*       sge4 = reinterpret_cast<float4*>(sge);
    for (int i = t; i < GPB * H / 4; i += 192) sge4[i] = ge4[i];
    __syncthreads();

    const float4* w4;
    float bias;
    if (t < FN) { w4 = reinterpret_cast<const float4*>(node_w + (size_t)t * H);      bias = node_b[t]; }
    else        { w4 = reinterpret_cast<const float4*>(edge_w + (size_t)(t-FN) * H); bias = edge_b[t-FN]; }

    float acc[GPB];
    #pragma unroll
    for (int g = 0; g < GPB; ++g) acc[g] = 0.f;

    #pragma unroll 4
    for (int k = 0; k < H / 4; ++k) {
        const float4 wv = w4[k];
        #pragma unroll
        for (int g = 0; g < GPB; ++g) {
            const float* s = sge + g * H + k * 4;   // same addr across lanes -> LDS broadcast
            acc[g] += wv.x * s[0] + wv.y * s[1] + wv.z * s[2] + wv.w * s[3];
        }
    }

    #pragma unroll
    for (int g = 0; g < GPB; ++g) {
        const float v = acc[g] + bias;
        if (t < FN) P[(size_t)(g0 + g) * FN + t]        = v;
        else        Q[(size_t)(g0 + g) * FE + (t - FN)] = v;
    }
}

// Node scatter: block owns rows [r0,r1). Stage ids + P rows [gLo..gHi] in LDS,
// then a pure LDS->nt-store loop (no vmcnt-dependent loads).
__global__ __launch_bounds__(256) void node_scatter(
    const int* __restrict__ batch,     // [N]
    const f4* __restrict__ P4,         // [B*32]
    f4* __restrict__ xout,             // [N*32]
    int N, int Bm1)
{
    __shared__ int sid[256];
    __shared__ f4  sP4[MAXG * 32];     // 16 KB
    const int b  = blockIdx.x;
    const int nb = gridDim.x;
    const int t  = threadIdx.x;

    const int r0 = (int)((long long)N * b / nb);
    const int r1 = (int)((long long)N * (b + 1) / nb);
    const int nR = r1 - r0;            // <= 245 at 2048 blocks

    for (int j = t; j < nR; j += 256) sid[j] = batch[r0 + j] & Bm1;
    __syncthreads();

    const int gLo = sid[0];
    const int nG  = sid[nR - 1] - gLo + 1;   // batch sorted -> contiguous graph range

    if (nG > 0 && nG <= MAXG) {
        // Stage P rows gLo..gLo+nG-1 (contiguous in memory -> coalesced f4 copy).
        const f4* srcP = P4 + ((size_t)gLo << 5);
        for (int j = t; j < (nG << 5); j += 256) sP4[j] = srcP[j];
        __syncthreads();
        const int tot = nR << 5;
        f4* outb = xout + ((size_t)r0 << 5);
        for (int k = t; k < tot; k += 256) {
            const int r = k >> 5, c = k & 31;
            const int g = sid[r] - gLo;
            __builtin_nontemporal_store(sP4[(g << 5) + c], outb + k);
        }
    } else {
        // Fallback (unsorted/degenerate input): direct gather.
        const int tot = nR << 5;
        f4* outb = xout + ((size_t)r0 << 5);
        for (int k = t; k < tot; k += 256) {
            const int r = k >> 5, c = k & 31;
            const int g = sid[r];
            __builtin_nontemporal_store(P4[(g << 5) + c], outb + k);
        }
    }
}

// Edge scatter: block owns edges [e0,e1). Stage eid = batch[src[e]] in LDS first
// (all staging loads issued before any store), then gather Q4 + nt-store.
__global__ __launch_bounds__(256) void edge_scatter(
    const int* __restrict__ batch,     // [N]
    const int* __restrict__ src,       // edge_index row 0
    const f4* __restrict__ Q4,         // [B*16]
    f4* __restrict__ eout,             // [E*16]
    int E, int N, int Bm1)
{
    __shared__ int eid[512];
    const int b  = blockIdx.x;
    const int nb = gridDim.x;
    const int t  = threadIdx.x;

    const int e0 = (int)((long long)E * b / nb);
    const int e1 = (int)((long long)E * (b + 1) / nb);
    const int nE = e1 - e0;            // <= 489 at 2048 blocks

    for (int j = t; j < nE; j += 256) {
        int s = src[e0 + j];
        s = min(max(s, 0), N - 1);
        eid[j] = batch[s] & Bm1;
    }
    __syncthreads();

    const int tot = nE << 4;
    f4* outb = eout + ((size_t)e0 << 4);
    for (int k = t; k < tot; k += 256) {
        const int e = k >> 4, c = k & 15;
        const int g = eid[e];
        __builtin_nontemporal_store(Q4[(g << 4) + c], outb + k);
    }
}

extern "C" void kernel_launch(void* const* d_in, const int* in_sizes, int n_in,
                              void* d_out, int out_size, void* d_ws, size_t ws_size,
                              hipStream_t stream) {
    const float* ge     = (const float*)d_in[0];
    const int*   batch  = (const int*)  d_in[1];
    const int*   eidx   = (const int*)  d_in[2];
    const float* node_w = (const float*)d_in[3];
    const float* node_b = (const float*)d_in[4];
    const float* edge_w = (const float*)d_in[5];
    const float* edge_b = (const float*)d_in[6];

    const int B = in_sizes[0] / H;   // 4096
    const int N = in_sizes[1];       // 500000
    const int E = in_sizes[2] / 2;   // 1000000

    float* P = (float*)d_ws;                 // [B, FN]  2 MB
    float* Q = P + (size_t)B * FN;           // [B, FE]  1 MB

    float* x_hat = (float*)d_out;            // [N, FN]
    float* e_hat = x_hat + (size_t)N * FN;   // [E, FE]

    proj_kernel<<<B / GPB, 192, 0, stream>>>(ge, node_w, node_b, edge_w, edge_b, P, Q);

    node_scatter<<<2048, 256, 0, stream>>>(batch, (const f4*)P, (f4*)x_hat, N, B - 1);
    edge_scatter<<<2048, 256, 0, stream>>>(batch, eidx, (const f4*)Q, (f4*)e_hat, E, N, B - 1);
}

// Round 6
// 119.975 us; speedup vs baseline: 1.1071x; 1.1071x over previous
//
#include <hip/hip_runtime.h>

// GNNDecoder: x_hat = GE[batch] @ node_w.T + node_b ; edge_hat = GE[batch[src]] @ edge_w.T + edge_b
// Structure: per-graph projections P=[B,FN], Q=[B,FE] (tiny GEMM), then outputs are
// pure row-gathers (memory-bound, 512MB nt-stores).
// R6 = exact R2 (proven 110.9us: fused barrier-free grid-stride scatter, nt stores)
//      + ONE change: explicit x2 unroll with batched loads in both scatter halves
//      (2 independent dependent-chains in flight per iteration).

#define H   256
#define FN  128
#define FE  64
#define GPB 8    // graphs per proj block

typedef float f4 __attribute__((ext_vector_type(4)));

__global__ __launch_bounds__(192) void proj_kernel(
    const float* __restrict__ ge,      // [B, H]
    const float* __restrict__ node_w,  // [FN, H]
    const float* __restrict__ node_b,  // [FN]
    const float* __restrict__ edge_w,  // [FE, H]
    const float* __restrict__ edge_b,  // [FE]
    float* __restrict__ P,             // [B, FN]
    float* __restrict__ Q)             // [B, FE]
{
    __shared__ float sge[GPB * H];
    const int t  = threadIdx.x;            // 0..191; waves 0,1 = node cols, wave 2 = edge cols
    const int g0 = blockIdx.x * GPB;

    const float4* ge4  = reinterpret_cast<const float4*>(ge + (size_t)g0 * H);
    float4*       sge4 = reinterpret_cast<float4*>(sge);
    for (int i = t; i < GPB * H / 4; i += 192) sge4[i] = ge4[i];
    __syncthreads();

    const float4* w4;
    float bias;
    if (t < FN) { w4 = reinterpret_cast<const float4*>(node_w + (size_t)t * H);      bias = node_b[t]; }
    else        { w4 = reinterpret_cast<const float4*>(edge_w + (size_t)(t-FN) * H); bias = edge_b[t-FN]; }

    float acc[GPB];
    #pragma unroll
    for (int g = 0; g < GPB; ++g) acc[g] = 0.f;

    #pragma unroll 4
    for (int k = 0; k < H / 4; ++k) {
        const float4 wv = w4[k];
        #pragma unroll
        for (int g = 0; g < GPB; ++g) {
            const float* s = sge + g * H + k * 4;   // same addr across lanes -> LDS broadcast
            acc[g] += wv.x * s[0] + wv.y * s[1] + wv.z * s[2] + wv.w * s[3];
        }
    }

    #pragma unroll
    for (int g = 0; g < GPB; ++g) {
        const float v = acc[g] + bias;
        if (t < FN) P[(size_t)(g0 + g) * FN + t]        = v;
        else        Q[(size_t)(g0 + g) * FE + (t - FN)] = v;
    }
}

// Fused scatter: first half of the grid streams x_hat, second half edge_hat.
// Barrier-free grid-stride; x2 unrolled with batched loads; nt stores.
__global__ __launch_bounds__(256) void scatter_fused(
    const int* __restrict__ batch,     // [N]
    const int* __restrict__ src,       // edge_index row 0 (E)
    const f4* __restrict__ P4,         // [B*32]
    const f4* __restrict__ Q4,         // [B*16]
    f4* __restrict__ xout,             // [N*32]
    f4* __restrict__ eout,             // [E*16]
    int n4, int e4, int halfBlocks, int Bm1, int Nm1)
{
    const int stride = halfBlocks * 256;
    if (blockIdx.x < (unsigned)halfBlocks) {
        // node phase: x_hat[i,:] = P[batch[i],:]
        int i = blockIdx.x * 256 + threadIdx.x;
        for (; i + stride < n4; i += 2 * stride) {
            const int j  = i + stride;
            const int g0 = batch[i >> 5] & Bm1;
            const int g1 = batch[j >> 5] & Bm1;
            const f4 v0 = P4[(g0 << 5) + (i & 31)];
            const f4 v1 = P4[(g1 << 5) + (j & 31)];
            __builtin_nontemporal_store(v0, xout + i);
            __builtin_nontemporal_store(v1, xout + j);
        }
        if (i < n4) {
            const int g = batch[i >> 5] & Bm1;
            __builtin_nontemporal_store(P4[(g << 5) + (i & 31)], xout + i);
        }
    } else {
        // edge phase: edge_hat[e,:] = Q[batch[src[e]],:]
        int i = (blockIdx.x - halfBlocks) * 256 + threadIdx.x;
        for (; i + stride < e4; i += 2 * stride) {
            const int j  = i + stride;
            int s0 = src[i >> 4];
            int s1 = src[j >> 4];
            s0 = min(max(s0, 0), Nm1);
            s1 = min(max(s1, 0), Nm1);
            const int g0 = batch[s0] & Bm1;
            const int g1 = batch[s1] & Bm1;
            const f4 v0 = Q4[(g0 << 4) + (i & 15)];
            const f4 v1 = Q4[(g1 << 4) + (j & 15)];
            __builtin_nontemporal_store(v0, eout + i);
            __builtin_nontemporal_store(v1, eout + j);
        }
        if (i < e4) {
            int s = src[i >> 4];
            s = min(max(s, 0), Nm1);
            const int g = batch[s] & Bm1;
            __builtin_nontemporal_store(Q4[(g << 4) + (i & 15)], eout + i);
        }
    }
}

extern "C" void kernel_launch(void* const* d_in, const int* in_sizes, int n_in,
                              void* d_out, int out_size, void* d_ws, size_t ws_size,
                              hipStream_t stream) {
    const float* ge     = (const float*)d_in[0];
    const int*   batch  = (const int*)  d_in[1];
    const int*   eidx   = (const int*)  d_in[2];
    const float* node_w = (const float*)d_in[3];
    const float* node_b = (const float*)d_in[4];
    const float* edge_w = (const float*)d_in[5];
    const float* edge_b = (const float*)d_in[6];

    const int B = in_sizes[0] / H;   // 4096
    const int N = in_sizes[1];       // 500000
    const int E = in_sizes[2] / 2;   // 1000000

    float* P = (float*)d_ws;                 // [B, FN]
    float* Q = P + (size_t)B * FN;           // [B, FE]

    float* x_hat = (float*)d_out;            // [N, FN]
    float* e_hat = x_hat + (size_t)N * FN;   // [E, FE]

    proj_kernel<<<B / GPB, 192, 0, stream>>>(ge, node_w, node_b, edge_w, edge_b, P, Q);

    const int n4 = N * (FN / 4);             // 16,000,000
    const int e4 = E * (FE / 4);             // 16,000,000
    const int halfBlocks = 1024;             // 2048 total = 8 blocks/CU resident
    scatter_fused<<<2 * halfBlocks, 256, 0, stream>>>(
        batch, eidx, (const f4*)P, (const f4*)Q, (f4*)x_hat, (f4*)e_hat,
        n4, e4, halfBlocks, B - 1, N - 1);
}

// Round 7
// 116.360 us; speedup vs baseline: 1.1415x; 1.0311x over previous
//
#include <hip/hip_runtime.h>

// GNNDecoder: x_hat = GE[batch] @ node_w.T + node_b ; edge_hat = GE[batch[src]] @ edge_w.T + edge_b
// Structure: per-graph projections P=[B,FN], Q=[B,FE] (tiny GEMM), then outputs are
// pure row-gathers (memory-bound, 512MB nt-stores).
// R7 = exact R2 (proven 110.9us) + ONE change: u16 index table.
//   batch16[n] = (u16)batch[n] precomputed in proj's epilogue. Shrinks the per-XCD
//   L2 hot set from 5MB (P 2 + Q 1 + batch 2) to 4MB so the edge leg's random
//   gathers stop thrashing L2; also halves node-leg index stream and removes
//   hot-loop clamps. (R3 barriers / R4 pairing / R5 staging / R6 unroll all
//   regressed -- R2 skeleton is load-bearing, do not touch.)

#define H   256
#define FN  128
#define FE  64
#define GPB 8    // graphs per proj block

typedef float f4 __attribute__((ext_vector_type(4)));

__global__ __launch_bounds__(192) void proj_kernel(
    const float* __restrict__ ge,      // [B, H]
    const float* __restrict__ node_w,  // [FN, H]
    const float* __restrict__ node_b,  // [FN]
    const float* __restrict__ edge_w,  // [FE, H]
    const float* __restrict__ edge_b,  // [FE]
    float* __restrict__ P,             // [B, FN]
    float* __restrict__ Q,             // [B, FE]
    const int* __restrict__ batch,     // [N]
    unsigned short* __restrict__ batch16, // [N] out
    int N, int Bm1)
{
    __shared__ float sge[GPB * H];
    const int t  = threadIdx.x;            // 0..191; waves 0,1 = node cols, wave 2 = edge cols
    const int g0 = blockIdx.x * GPB;

    const float4* ge4  = reinterpret_cast<const float4*>(ge + (size_t)g0 * H);
    float4*       sge4 = reinterpret_cast<float4*>(sge);
    for (int i = t; i < GPB * H / 4; i += 192) sge4[i] = ge4[i];
    __syncthreads();

    const float4* w4;
    float bias;
    if (t < FN) { w4 = reinterpret_cast<const float4*>(node_w + (size_t)t * H);      bias = node_b[t]; }
    else        { w4 = reinterpret_cast<const float4*>(edge_w + (size_t)(t-FN) * H); bias = edge_b[t-FN]; }

    float acc[GPB];
    #pragma unroll
    for (int g = 0; g < GPB; ++g) acc[g] = 0.f;

    #pragma unroll 4
    for (int k = 0; k < H / 4; ++k) {
        const float4 wv = w4[k];
        #pragma unroll
        for (int g = 0; g < GPB; ++g) {
            const float* s = sge + g * H + k * 4;   // same addr across lanes -> LDS broadcast
            acc[g] += wv.x * s[0] + wv.y * s[1] + wv.z * s[2] + wv.w * s[3];
        }
    }

    #pragma unroll
    for (int g = 0; g < GPB; ++g) {
        const float v = acc[g] + bias;
        if (t < FN) P[(size_t)(g0 + g) * FN + t]        = v;
        else        Q[(size_t)(g0 + g) * FE + (t - FN)] = v;
    }

    // Epilogue: convert batch -> u16 (clamped), grid-stride across the whole grid.
    const int tid = blockIdx.x * 192 + t;
    const int gs  = gridDim.x * 192;
    for (int n = tid; n < N; n += gs)
        batch16[n] = (unsigned short)(batch[n] & Bm1);
}

// Fused scatter: first half of the grid streams x_hat, second half edge_hat.
// Barrier-free grid-stride, nt stores, u16 index table (L2-fitting hot set).
__global__ __launch_bounds__(256) void scatter_fused(
    const unsigned short* __restrict__ batch16, // [N], pre-clamped
    const int* __restrict__ src,       // edge_index row 0 (E)
    const f4* __restrict__ P4,         // [B*32]
    const f4* __restrict__ Q4,         // [B*16]
    f4* __restrict__ xout,             // [N*32]
    f4* __restrict__ eout,             // [E*16]
    int n4, int e4, int halfBlocks, int Nm1)
{
    const int stride = halfBlocks * 256;
    if (blockIdx.x < (unsigned)halfBlocks) {
        // node phase: x_hat[i,:] = P[batch[i],:]
        for (int i = blockIdx.x * 256 + threadIdx.x; i < n4; i += stride) {
            const int row = i >> 5;
            const int c   = i & 31;
            const int g   = batch16[row];
            __builtin_nontemporal_store(P4[(g << 5) + c], xout + i);
        }
    } else {
        // edge phase: edge_hat[e,:] = Q[batch[src[e]],:]
        for (int i = (blockIdx.x - halfBlocks) * 256 + threadIdx.x; i < e4; i += stride) {
            const int e = i >> 4;
            const int c = i & 15;
            int s = src[e];
            s = min(max(s, 0), Nm1);
            const int g = batch16[s];
            __builtin_nontemporal_store(Q4[(g << 4) + c], eout + i);
        }
    }
}

extern "C" void kernel_launch(void* const* d_in, const int* in_sizes, int n_in,
                              void* d_out, int out_size, void* d_ws, size_t ws_size,
                              hipStream_t stream) {
    const float* ge     = (const float*)d_in[0];
    const int*   batch  = (const int*)  d_in[1];
    const int*   eidx   = (const int*)  d_in[2];
    const float* node_w = (const float*)d_in[3];
    const float* node_b = (const float*)d_in[4];
    const float* edge_w = (const float*)d_in[5];
    const float* edge_b = (const float*)d_in[6];

    const int B = in_sizes[0] / H;   // 4096
    const int N = in_sizes[1];       // 500000
    const int E = in_sizes[2] / 2;   // 1000000

    float* P = (float*)d_ws;                          // [B, FN]  2 MB
    float* Q = P + (size_t)B * FN;                    // [B, FE]  1 MB
    unsigned short* batch16 =
        (unsigned short*)(Q + (size_t)B * FE);        // [N]      1 MB

    float* x_hat = (float*)d_out;            // [N, FN]
    float* e_hat = x_hat + (size_t)N * FN;   // [E, FE]

    proj_kernel<<<B / GPB, 192, 0, stream>>>(ge, node_w, node_b, edge_w, edge_b,
                                             P, Q, batch, batch16, N, B - 1);

    const int n4 = N * (FN / 4);             // 16,000,000
    const int e4 = E * (FE / 4);             // 16,000,000
    const int halfBlocks = 1024;             // 2048 total = 8 blocks/CU resident
    scatter_fused<<<2 * halfBlocks, 256, 0, stream>>>(
        batch16, eidx, (const f4*)P, (const f4*)Q, (f4*)x_hat, (f4*)e_hat,
        n4, e4, halfBlocks, N - 1);
}

// Round 8
// 112.425 us; speedup vs baseline: 1.1815x; 1.0350x over previous
//
#include <hip/hip_runtime.h>

// GNNDecoder: x_hat = GE[batch] @ node_w.T + node_b ; edge_hat = GE[batch[src]] @ edge_w.T + edge_b
// Structure: per-graph projections P=[B,FN], Q=[B,FE] (tiny GEMM), then outputs are
// pure row-gathers (memory-bound, 512MB nt-stores).
// R8 = exact R2 (proven best 110.9us) + ONE change: node/edge phase split by XCD
// parity ((blockIdx&7)<4 -> node) instead of lower/upper block halves. Per-XCD L2
// then holds only its phase's tables (node: P 2MB + batch 2MB = 4MB fits; edge:
// Q 1MB + batch-random 2MB = 3MB fits) instead of the 5MB union thrashing 4MB L2.
// If the blockIdx%8->XCD assumption is wrong this is bit-identical work to R2.
// (R3 barriers / R4 pairing / R5 staging / R6 unroll / R7 u16 all regressed.)

#define H   256
#define FN  128
#define FE  64
#define GPB 8    // graphs per proj block

typedef float f4 __attribute__((ext_vector_type(4)));

__global__ __launch_bounds__(192) void proj_kernel(
    const float* __restrict__ ge,      // [B, H]
    const float* __restrict__ node_w,  // [FN, H]
    const float* __restrict__ node_b,  // [FN]
    const float* __restrict__ edge_w,  // [FE, H]
    const float* __restrict__ edge_b,  // [FE]
    float* __restrict__ P,             // [B, FN]
    float* __restrict__ Q)             // [B, FE]
{
    __shared__ float sge[GPB * H];
    const int t  = threadIdx.x;            // 0..191; waves 0,1 = node cols, wave 2 = edge cols
    const int g0 = blockIdx.x * GPB;

    const float4* ge4  = reinterpret_cast<const float4*>(ge + (size_t)g0 * H);
    float4*       sge4 = reinterpret_cast<float4*>(sge);
    for (int i = t; i < GPB * H / 4; i += 192) sge4[i] = ge4[i];
    __syncthreads();

    const float4* w4;
    float bias;
    if (t < FN) { w4 = reinterpret_cast<const float4*>(node_w + (size_t)t * H);      bias = node_b[t]; }
    else        { w4 = reinterpret_cast<const float4*>(edge_w + (size_t)(t-FN) * H); bias = edge_b[t-FN]; }

    float acc[GPB];
    #pragma unroll
    for (int g = 0; g < GPB; ++g) acc[g] = 0.f;

    #pragma unroll 4
    for (int k = 0; k < H / 4; ++k) {
        const float4 wv = w4[k];
        #pragma unroll
        for (int g = 0; g < GPB; ++g) {
            const float* s = sge + g * H + k * 4;   // same addr across lanes -> LDS broadcast
            acc[g] += wv.x * s[0] + wv.y * s[1] + wv.z * s[2] + wv.w * s[3];
        }
    }

    #pragma unroll
    for (int g = 0; g < GPB; ++g) {
        const float v = acc[g] + bias;
        if (t < FN) P[(size_t)(g0 + g) * FN + t]        = v;
        else        Q[(size_t)(g0 + g) * FE + (t - FN)] = v;
    }
}

// Fused scatter. Phase chosen by XCD parity: (blockIdx&7)<4 -> node, else edge.
// Virtual block id within phase: q*4 + (r or r-4); 1024 virtual blocks per phase.
// Loop bodies identical to R2.
__global__ __launch_bounds__(256) void scatter_fused(
    const int* __restrict__ batch,     // [N]
    const int* __restrict__ src,       // edge_index row 0 (E)
    const f4* __restrict__ P4,         // [B*32]
    const f4* __restrict__ Q4,         // [B*16]
    f4* __restrict__ xout,             // [N*32]
    f4* __restrict__ eout,             // [E*16]
    int n4, int e4, int halfBlocks, int Bm1, int Nm1)
{
    const int stride = halfBlocks * 256;
    const int q = blockIdx.x >> 3;
    const int r = blockIdx.x & 7;
    if (r < 4) {
        // node phase on XCDs 0-3: x_hat[i,:] = P[batch[i],:]
        const int vb = q * 4 + r;              // 0..1023
        for (int i = vb * 256 + threadIdx.x; i < n4; i += stride) {
            const int row = i >> 5;
            const int c   = i & 31;
            const int g   = batch[row] & Bm1;
            __builtin_nontemporal_store(P4[(g << 5) + c], xout + i);
        }
    } else {
        // edge phase on XCDs 4-7: edge_hat[e,:] = Q[batch[src[e]],:]
        const int vb = q * 4 + (r - 4);        // 0..1023
        for (int i = vb * 256 + threadIdx.x; i < e4; i += stride) {
            const int e = i >> 4;
            const int c = i & 15;
            int s = src[e];
            s = min(max(s, 0), Nm1);
            const int g = batch[s] & Bm1;
            __builtin_nontemporal_store(Q4[(g << 4) + c], eout + i);
        }
    }
}

extern "C" void kernel_launch(void* const* d_in, const int* in_sizes, int n_in,
                              void* d_out, int out_size, void* d_ws, size_t ws_size,
                              hipStream_t stream) {
    const float* ge     = (const float*)d_in[0];
    const int*   batch  = (const int*)  d_in[1];
    const int*   eidx   = (const int*)  d_in[2];
    const float* node_w = (const float*)d_in[3];
    const float* node_b = (const float*)d_in[4];
    const float* edge_w = (const float*)d_in[5];
    const float* edge_b = (const float*)d_in[6];

    const int B = in_sizes[0] / H;   // 4096
    const int N = in_sizes[1];       // 500000
    const int E = in_sizes[2] / 2;   // 1000000

    float* P = (float*)d_ws;                 // [B, FN]  2 MB
    float* Q = P + (size_t)B * FN;           // [B, FE]  1 MB

    float* x_hat = (float*)d_out;            // [N, FN]
    float* e_hat = x_hat + (size_t)N * FN;   // [E, FE]

    proj_kernel<<<B / GPB, 192, 0, stream>>>(ge, node_w, node_b, edge_w, edge_b, P, Q);

    const int n4 = N * (FN / 4);             // 16,000,000
    const int e4 = E * (FE / 4);             // 16,000,000
    const int halfBlocks = 1024;             // 2048 total = 8 blocks/CU resident
    scatter_fused<<<2 * halfBlocks, 256, 0, stream>>>(
        batch, eidx, (const f4*)P, (const f4*)Q, (f4*)x_hat, (f4*)e_hat,
        n4, e4, halfBlocks, B - 1, N - 1);
}

// Round 9
// 111.874 us; speedup vs baseline: 1.1873x; 1.0049x over previous
//
#include <hip/hip_runtime.h>

// GNNDecoder: x_hat = GE[batch] @ node_w.T + node_b ; edge_hat = GE[batch[src]] @ edge_w.T + edge_b
// Structure: per-graph projections P=[B,FN], Q=[B,FE] (tiny GEMM), then outputs are
// pure row-gathers (memory-bound, 512MB nt-stores).
// R9 = exact R2 restoration (best measured: 110.9us).
// Falsified residual theories (each a single-variable experiment off this base):
//   R3 barrier-chunked staging  127.7  (syncthreads drains nt-store queue)
//   R4 paired chains + eg[]     128.1
//   R5 LDS row staging          132.8  (pure LDS->store loop NOT faster: loads
//                                       don't stall on store queue)
//   R6 x2 unroll                120.0  (chain latency already hidden at 32 w/CU)
//   R7 u16 index table          116.4
//   R8 XCD-parity phase split   112.4  (neutral -> per-XCD L2 capacity not the limiter)
// Conclusion: gather + nt-store mix sustains ~5.7 TB/s vs 6.85 TB/s pure-write
// fill; 512MB writes / 5.7 TB/s + proj(~6us) + launches = ~111us. Empirical
// mixed-stream roofline.

#define H   256
#define FN  128
#define FE  64
#define GPB 8    // graphs per proj block

typedef float f4 __attribute__((ext_vector_type(4)));

__global__ __launch_bounds__(192) void proj_kernel(
    const float* __restrict__ ge,      // [B, H]
    const float* __restrict__ node_w,  // [FN, H]
    const float* __restrict__ node_b,  // [FN]
    const float* __restrict__ edge_w,  // [FE, H]
    const float* __restrict__ edge_b,  // [FE]
    float* __restrict__ P,             // [B, FN]
    float* __restrict__ Q)             // [B, FE]
{
    __shared__ float sge[GPB * H];
    const int t  = threadIdx.x;            // 0..191; waves 0,1 = node cols, wave 2 = edge cols
    const int g0 = blockIdx.x * GPB;

    const float4* ge4  = reinterpret_cast<const float4*>(ge + (size_t)g0 * H);
    float4*       sge4 = reinterpret_cast<float4*>(sge);
    for (int i = t; i < GPB * H / 4; i += 192) sge4[i] = ge4[i];
    __syncthreads();

    const float4* w4;
    float bias;
    if (t < FN) { w4 = reinterpret_cast<const float4*>(node_w + (size_t)t * H);      bias = node_b[t]; }
    else        { w4 = reinterpret_cast<const float4*>(edge_w + (size_t)(t-FN) * H); bias = edge_b[t-FN]; }

    float acc[GPB];
    #pragma unroll
    for (int g = 0; g < GPB; ++g) acc[g] = 0.f;

    #pragma unroll 4
    for (int k = 0; k < H / 4; ++k) {
        const float4 wv = w4[k];
        #pragma unroll
        for (int g = 0; g < GPB; ++g) {
            const float* s = sge + g * H + k * 4;   // same addr across lanes -> LDS broadcast
            acc[g] += wv.x * s[0] + wv.y * s[1] + wv.z * s[2] + wv.w * s[3];
        }
    }

    #pragma unroll
    for (int g = 0; g < GPB; ++g) {
        const float v = acc[g] + bias;
        if (t < FN) P[(size_t)(g0 + g) * FN + t]        = v;
        else        Q[(size_t)(g0 + g) * FE + (t - FN)] = v;
    }
}

// Fused scatter: first half of the grid streams x_hat, second half edge_hat.
// Barrier-free grid-stride; nt stores (write stream must not allocate in L2).
__global__ __launch_bounds__(256) void scatter_fused(
    const int* __restrict__ batch,     // [N]
    const int* __restrict__ src,       // edge_index row 0 (E)
    const f4* __restrict__ P4,         // [B*32]
    const f4* __restrict__ Q4,         // [B*16]
    f4* __restrict__ xout,             // [N*32]
    f4* __restrict__ eout,             // [E*16]
    int n4, int e4, int halfBlocks, int Bm1, int Nm1)
{
    const int stride = halfBlocks * 256;
    if (blockIdx.x < (unsigned)halfBlocks) {
        // node phase: x_hat[i,:] = P[batch[i],:]
        for (int i = blockIdx.x * 256 + threadIdx.x; i < n4; i += stride) {
            const int row = i >> 5;
            const int c   = i & 31;
            const int g   = batch[row] & Bm1;
            __builtin_nontemporal_store(P4[(g << 5) + c], xout + i);
        }
    } else {
        // edge phase: edge_hat[e,:] = Q[batch[src[e]],:]
        for (int i = (blockIdx.x - halfBlocks) * 256 + threadIdx.x; i < e4; i += stride) {
            const int e = i >> 4;
            const int c = i & 15;
            int s = src[e];
            s = min(max(s, 0), Nm1);
            const int g = batch[s] & Bm1;
            __builtin_nontemporal_store(Q4[(g << 4) + c], eout + i);
        }
    }
}

extern "C" void kernel_launch(void* const* d_in, const int* in_sizes, int n_in,
                              void* d_out, int out_size, void* d_ws, size_t ws_size,
                              hipStream_t stream) {
    const float* ge     = (const float*)d_in[0];
    const int*   batch  = (const int*)  d_in[1];
    const int*   eidx   = (const int*)  d_in[2];
    const float* node_w = (const float*)d_in[3];
    const float* node_b = (const float*)d_in[4];
    const float* edge_w = (const float*)d_in[5];
    const float* edge_b = (const float*)d_in[6];

    const int B = in_sizes[0] / H;   // 4096
    const int N = in_sizes[1];       // 500000
    const int E = in_sizes[2] / 2;   // 1000000

    float* P = (float*)d_ws;                 // [B, FN]  2 MB
    float* Q = P + (size_t)B * FN;           // [B, FE]  1 MB

    float* x_hat = (float*)d_out;            // [N, FN]
    float* e_hat = x_hat + (size_t)N * FN;   // [E, FE]

    proj_kernel<<<B / GPB, 192, 0, stream>>>(ge, node_w, node_b, edge_w, edge_b, P, Q);

    const int n4 = N * (FN / 4);             // 16,000,000
    const int e4 = E * (FE / 4);             // 16,000,000
    const int halfBlocks = 1024;             // 2048 total = 8 blocks/CU resident
    scatter_fused<<<2 * halfBlocks, 256, 0, stream>>>(
        batch, eidx, (const f4*)P, (const f4*)Q, (f4*)x_hat, (f4*)e_hat,
        n4, e4, halfBlocks, B - 1, N - 1);
}